// Round 3
// baseline (1207.220 us; speedup 1.0000x reference)
//
#include <hip/hip_runtime.h>

#define NN 10000
#define NE 160000
#define NG 64
#define NT 5
#define NF 75
#define NL 4
#define LOG17 2.8332133f  /* log(17.0) */
#define ROW1 960          /* out1 row: B 5*96 | base 5*96 (96-pad = 3 cache lines) */
#define WCN 1152          /* Wcat cols: B 480 | base 480 | y0 75 | pad (9 j-tiles of 128) */

// ---------------------------------------------------------------- setup
__global__ __launch_bounds__(256) void k_init_h(const float* __restrict__ x,
    const float* __restrict__ W, const float* __restrict__ b, float* __restrict__ h){
  int i = blockIdx.x*256 + threadIdx.x;
  if (i >= NN*NF) return;
  int n = i / NF, f = i - n*NF;
  h[i] = x[2*n]*W[f] + x[2*n+1]*W[NF+f] + b[f];
}

__global__ __launch_bounds__(256) void k_count(const int* __restrict__ ei, int* __restrict__ cnt){
  int e = blockIdx.x*256 + threadIdx.x;
  if (e < NE) atomicAdd(&cnt[ei[NE + e]], 1);   // row 1 = dst
}

__global__ __launch_bounds__(1024) void k_scan(const int* __restrict__ cnt,
    int* __restrict__ off, int* __restrict__ cur){
  __shared__ int buf[1024];
  __shared__ int carry;
  int tid = threadIdx.x;
  if (tid == 0) carry = 0;
  __syncthreads();
  for (int base = 0; base < NN; base += 1024){
    int i = base + tid;
    int v = (i < NN) ? cnt[i] : 0;
    buf[tid] = v;
    __syncthreads();
    for (int d = 1; d < 1024; d <<= 1){
      int t = (tid >= d) ? buf[tid - d] : 0;
      __syncthreads();
      buf[tid] += t;
      __syncthreads();
    }
    int c = carry;
    if (i < NN){ int ex = c + buf[tid] - v; off[i] = ex; cur[i] = ex; }
    int tot = buf[1023];
    __syncthreads();
    if (tid == 0) carry = c + tot;
    __syncthreads();
  }
  if (tid == 0) off[NN] = NE;
}

__global__ __launch_bounds__(256) void k_scatter(const int* __restrict__ ei,
    int* __restrict__ cur, int* __restrict__ csr){
  int e = blockIdx.x*256 + threadIdx.x;
  if (e < NE){
    int d = ei[NE + e];
    int p = atomicAdd(&cur[d], 1);
    csr[p] = ei[e];   // src node
  }
}

// Wcat[l][75][1152]: 0..479 Wbot (t=j/96,f=j%96,f<75), 480..959 Wtop, 960..1034 y0, rest 0
__global__ __launch_bounds__(256) void k_buildWcat(const float* __restrict__ preW,
    const float* __restrict__ postW, float* __restrict__ Wcat){
  int idx = blockIdx.x*256 + threadIdx.x;
  if (idx >= NL*75*WCN) return;
  int l = idx / (75*WCN);
  int rem = idx - l*75*WCN;
  int c = rem / WCN, j = rem - c*WCN;
  float v = 0.f;
  if (j < 480){
    int t = j/96, f = j - t*96;
    if (f < 75) v = preW[(size_t)((l*NT + t)*150 + 75 + c)*75 + f];
  } else if (j < 960){
    int jj = j - 480; int t = jj/96, f = jj - t*96;
    if (f < 75) v = preW[(size_t)((l*NT + t)*150 + c)*75 + f];
  } else if (j < 1035){
    int jj = j - 960; int t = jj/15, f2 = jj - t*15;
    v = postW[(size_t)((l*NT + t)*975 + c)*15 + f2];
  }
  Wcat[idx] = v;
}

// W45[l][t][300][48]: col g*15+f2 = postW row (75 + g*300 + c), col f2. pads 0.
__global__ __launch_bounds__(256) void k_buildW45(const float* __restrict__ postW,
    float* __restrict__ W45){
  int idx = blockIdx.x*256 + threadIdx.x;
  if (idx >= NL*NT*300*48) return;
  int l = idx / (NT*300*48);
  int rem = idx - l*NT*300*48;
  int t = rem / (300*48);
  int rem2 = rem - t*300*48;
  int c = rem2 / 48, f48 = rem2 - c*48;
  float v = 0.f;
  if (f48 < 45){
    int g = f48/15, f2 = f48 - g*15;
    v = postW[(size_t)((l*NT + t)*975 + 75 + g*300 + c)*15 + f2];
  }
  W45[idx] = v;
}

// ------ GEMM1: [B|base(+preb)|y0] = src(BN?) @ Wcat.  M=10000, K=75, N=1152
__global__ __launch_bounds__(256) void k_gemm1(const float* __restrict__ src,
    const float* __restrict__ Wcat, const float* __restrict__ preb,
    const float* __restrict__ bnSp, const float* __restrict__ sc,
    const float* __restrict__ bb, int use_bn,
    float* __restrict__ out1, float* __restrict__ z, int l){
  __shared__ float As[75][68];
  __shared__ float Ws[75][128];
  int tid = threadIdx.x;
  int bid = blockIdx.x;
  int nt = bid / 9, jt = bid - nt*9;
  int n0 = nt*64, j0 = jt*128;

  for (int idx = tid; idx < 64*75; idx += 256){
    int i = idx/75, c = idx - i*75;
    float v = (n0 + i < NN) ? src[(size_t)n0*75 + idx] : 0.f;
    if (use_bn){
      float mu = bnSp[c] * (1.f/NN);
      float var = bnSp[80 + c] * (1.f/NN) - mu*mu;
      v = fmaxf((v - mu) / sqrtf(var + 1e-5f) * sc[c] + bb[c], 0.f);
    }
    As[c][i] = v;
  }
  const float* wg = Wcat + (size_t)l*75*WCN;
  for (int idx = tid; idx < 75*128; idx += 256){
    int c = idx >> 7, j = idx & 127;
    Ws[c][j] = wg[(size_t)c*WCN + j0 + j];
  }
  __syncthreads();

  int jj = tid >> 4, n4 = tid & 15;
  float acc[4][8];
  #pragma unroll
  for (int i = 0; i < 4; ++i)
    #pragma unroll
    for (int j = 0; j < 8; ++j) acc[i][j] = 0.f;

  for (int c = 0; c < 75; ++c){
    float4 a = *reinterpret_cast<const float4*>(&As[c][n4*4]);
    float4 w0 = *reinterpret_cast<const float4*>(&Ws[c][jj*8]);
    float4 w1 = *reinterpret_cast<const float4*>(&Ws[c][jj*8 + 4]);
    float av[4] = {a.x, a.y, a.z, a.w};
    float wv[8] = {w0.x, w0.y, w0.z, w0.w, w1.x, w1.y, w1.z, w1.w};
    #pragma unroll
    for (int i = 0; i < 4; ++i)
      #pragma unroll
      for (int j = 0; j < 8; ++j) acc[i][j] += av[i]*wv[j];
  }

  #pragma unroll
  for (int i = 0; i < 4; ++i){
    int n = n0 + n4*4 + i;
    if (n >= NN) continue;
    #pragma unroll
    for (int j = 0; j < 8; ++j){
      int col = j0 + jj*8 + j;
      float v = acc[i][j];
      if (col < 480){
        out1[(size_t)n*ROW1 + col] = v;
      } else if (col < 960){
        int cc = col - 480; int tt = cc/96, f = cc - tt*96;
        float pv = (f < 75) ? preb[l*375 + tt*75 + f] : 0.f;
        out1[(size_t)n*ROW1 + col] = v + pv;
      } else if (col < 1035){
        z[(size_t)n*75 + (col - 960)] = v;
      }
    }
  }
}

// ---- fused gather-aggregate + post-GEMM (K=300,N=45) + scalers. 256 thr.
// block = (32-node tile, tower). 8 threads/node, each owns float4s {r, r+8, r+16}
__global__ __launch_bounds__(256) void k_aggpost(
    const float* __restrict__ out1, float* __restrict__ z,
    const int* __restrict__ off, const int* __restrict__ csr,
    const float* __restrict__ W45, const float* __restrict__ postb, int l){
  __shared__ float As[60][36];
  __shared__ float Ws[60][64];
  __shared__ float dln[32];
  int tid = threadIdx.x;
  int bid = blockIdx.x;
  int nt = bid / NT, t = bid - nt*NT;
  int n0 = nt*32;

  int n_loc = tid >> 3, r = tid & 7;
  int n = n0 + n_loc;

  float s[12], ss[12], mnv[12], mxv[12];
  #pragma unroll
  for (int j = 0; j < 12; ++j){ s[j]=0.f; ss[j]=0.f; mnv[j]=3.4e38f; mxv[j]=-3.4e38f; }
  int deg = 0; float d = 1.f;

#define ACC4(V,J) { \
    s[J]+=V.x; ss[J]+=V.x*V.x; mnv[J]=fminf(mnv[J],V.x); mxv[J]=fmaxf(mxv[J],V.x); \
    s[J+1]+=V.y; ss[J+1]+=V.y*V.y; mnv[J+1]=fminf(mnv[J+1],V.y); mxv[J+1]=fmaxf(mxv[J+1],V.y); \
    s[J+2]+=V.z; ss[J+2]+=V.z*V.z; mnv[J+2]=fminf(mnv[J+2],V.z); mxv[J+2]=fmaxf(mxv[J+2],V.z); \
    s[J+3]+=V.w; ss[J+3]+=V.w*V.w; mnv[J+3]=fminf(mnv[J+3],V.w); mxv[J+3]=fmaxf(mxv[J+3],V.w); }

  if (n < NN){
    int e0 = off[n], e1 = off[n+1];
    deg = e1 - e0;
    d = (float)(deg > 0 ? deg : 1);
    int fo = 4*r;   // float offset of chunk0 within 96-slice
    int k = e0;
    for (; k + 2 <= e1; k += 2){
      int i0 = csr[k], i1 = csr[k+1];
      const float* p0 = out1 + (size_t)i0*ROW1 + t*96 + fo;
      const float* p1 = out1 + (size_t)i1*ROW1 + t*96 + fo;
      float4 a0 = *reinterpret_cast<const float4*>(p0);
      float4 a1 = *reinterpret_cast<const float4*>(p0 + 32);
      float4 a2 = *reinterpret_cast<const float4*>(p0 + 64);
      float4 b0 = *reinterpret_cast<const float4*>(p1);
      float4 b1 = *reinterpret_cast<const float4*>(p1 + 32);
      float4 b2 = *reinterpret_cast<const float4*>(p1 + 64);
      ACC4(a0,0) ACC4(a1,4) ACC4(a2,8)
      ACC4(b0,0) ACC4(b1,4) ACC4(b2,8)
    }
    if (k < e1){
      int i0 = csr[k];
      const float* p0 = out1 + (size_t)i0*ROW1 + t*96 + fo;
      float4 a0 = *reinterpret_cast<const float4*>(p0);
      float4 a1 = *reinterpret_cast<const float4*>(p0 + 32);
      float4 a2 = *reinterpret_cast<const float4*>(p0 + 64);
      ACC4(a0,0) ACC4(a1,4) ACC4(a2,8)
    }
    // finalize: combine base, compute [mean, mn, mx, sd]
    const float* basep = out1 + (size_t)n*ROW1 + 480 + t*96;
    if (deg > 0){
      #pragma unroll
      for (int j = 0; j < 12; ++j){
        int f = (j >> 2)*32 + 4*r + (j & 3);
        if (f < 75){
          float bs = basep[f];
          float mb = s[j] / d;
          float var = ss[j] / d - mb*mb;
          s[j]  = bs + mb;
          ss[j] = sqrtf(fmaxf(var, 0.f) + 1e-5f);
          mnv[j] = bs + mnv[j];
          mxv[j] = bs + mxv[j];
        }
      }
    } else {
      #pragma unroll
      for (int j = 0; j < 12; ++j){ s[j]=0.f; ss[j]=sqrtf(1e-5f); mnv[j]=0.f; mxv[j]=0.f; }
    }
    if (r == 0) dln[n_loc] = d;
  }
#undef ACC4

  // ---------- GEMM over K=300 in 5 chunks of 60, A staged from regs
  int nq = tid & 15, fg = tid >> 4;      // nodes nq*2..+1, f48 = fg*3..+2
  float acc[2][3];
  #pragma unroll
  for (int i = 0; i < 2; ++i){ acc[i][0]=0.f; acc[i][1]=0.f; acc[i][2]=0.f; }
  const float* wg = W45 + (size_t)(l*NT + t)*300*48;

  for (int ch = 0; ch < 5; ++ch){
    int c0 = ch*60;
    for (int idx = tid; idx < 60*48; idx += 256){
      int cc = idx / 48, f48 = idx - cc*48;
      Ws[cc][(f48/3)*4 + (f48 - (f48/3)*3)] = wg[(size_t)(c0 + cc)*48 + f48];
    }
    if (n < NN){
      #pragma unroll
      for (int j = 0; j < 12; ++j){
        int f = (j >> 2)*32 + 4*r + (j & 3);
        if (f < 75){
          int c;
          c = f;       if (c >= c0 && c < c0+60) As[c - c0][n_loc] = s[j];
          c = 75 + f;  if (c >= c0 && c < c0+60) As[c - c0][n_loc] = mnv[j];
          c = 150 + f; if (c >= c0 && c < c0+60) As[c - c0][n_loc] = mxv[j];
          c = 225 + f; if (c >= c0 && c < c0+60) As[c - c0][n_loc] = ss[j];
        }
      }
    }
    __syncthreads();
    for (int cc = 0; cc < 60; ++cc){
      float2 a = *reinterpret_cast<const float2*>(&As[cc][nq*2]);
      float4 w = *reinterpret_cast<const float4*>(&Ws[cc][fg*4]);
      acc[0][0] += a.x*w.x; acc[0][1] += a.x*w.y; acc[0][2] += a.x*w.z;
      acc[1][0] += a.y*w.x; acc[1][1] += a.y*w.y; acc[1][2] += a.y*w.z;
    }
    __syncthreads();
  }

  // ---------- partials -> LDS, combine with scalers into z
  float* part = &As[0][0];       // [48][36]
  #pragma unroll
  for (int e = 0; e < 3; ++e){
    int f48 = fg*3 + e;
    part[f48*36 + nq*2]     = acc[0][e];
    part[f48*36 + nq*2 + 1] = acc[1][e];
  }
  __syncthreads();
  for (int idx = tid; idx < 32*15; idx += 256){
    int nl = idx / 15, f2 = idx - nl*15;
    int nn = n0 + nl;
    if (nn < NN){
      float dd = dln[nl];
      float logd = logf(dd + 1.f);
      float amp = logd / LOG17, att = LOG17 / logd;
      float g0 = part[f2*36 + nl];
      float g1 = part[(15 + f2)*36 + nl];
      float g2 = part[(30 + f2)*36 + nl];
      size_t zi = (size_t)nn*75 + t*15 + f2;
      z[zi] = z[zi] + g0 + amp*g1 + att*g2 + postb[(l*NT + t)*15 + f2];
    }
  }
}

// ------ mixing lin: out2 = z @ linW + linb; fused BN partial sums (atomics)
__global__ __launch_bounds__(256) void k_lin(const float* __restrict__ z,
    const float* __restrict__ linW, const float* __restrict__ linb,
    float* __restrict__ out2, float* __restrict__ bnS1, int l){
  __shared__ float zs[75][68];
  __shared__ float lw[75][80];
  int tid = threadIdx.x;
  int n0 = blockIdx.x*64;
  for (int idx = tid; idx < 64*75; idx += 256){
    int i = idx/75, c = idx - i*75;
    zs[c][i] = (n0 + i < NN) ? z[(size_t)n0*75 + idx] : 0.f;
  }
  for (int idx = tid; idx < 75*80; idx += 256){
    int c = idx/80, o = idx - c*80;
    lw[c][o] = (o < 75) ? linW[(size_t)l*5625 + c*75 + o] : 0.f;
  }
  __syncthreads();
  int og = tid >> 4, n4 = tid & 15;
  int o0 = og*5;
  float acc[4][5];
  #pragma unroll
  for (int i = 0; i < 4; ++i)
    #pragma unroll
    for (int k = 0; k < 5; ++k) acc[i][k] = 0.f;
  for (int c = 0; c < 75; ++c){
    float4 a = *reinterpret_cast<const float4*>(&zs[c][n4*4]);
    float av[4] = {a.x, a.y, a.z, a.w};
    float wv[5];
    #pragma unroll
    for (int k = 0; k < 5; ++k) wv[k] = lw[c][o0 + k];
    #pragma unroll
    for (int i = 0; i < 4; ++i)
      #pragma unroll
      for (int k = 0; k < 5; ++k) acc[i][k] += av[i]*wv[k];
  }
  float s1p[5], s2p[5];
  #pragma unroll
  for (int k = 0; k < 5; ++k){ s1p[k] = 0.f; s2p[k] = 0.f; }
  #pragma unroll
  for (int i = 0; i < 4; ++i){
    int n = n0 + n4*4 + i;
    if (n >= NN) continue;
    #pragma unroll
    for (int k = 0; k < 5; ++k){
      int o = o0 + k;
      if (o < 75){
        float v = acc[i][k] + linb[l*75 + o];
        out2[(size_t)n*75 + o] = v;
        s1p[k] += v; s2p[k] += v*v;
      }
    }
  }
  // column-sum reduce into bnS via LDS (reuse zs region)
  __syncthreads();
  float* red = &zs[0][0];          // [75][16] s1, then [75][16] s2
  #pragma unroll
  for (int k = 0; k < 5; ++k){
    int o = o0 + k;
    if (o < 75){ red[o*16 + n4] = s1p[k]; red[1200 + o*16 + n4] = s2p[k]; }
  }
  __syncthreads();
  if (tid < 75){
    float a1 = 0.f, a2 = 0.f;
    #pragma unroll
    for (int j = 0; j < 16; ++j){ a1 += red[tid*16 + j]; a2 += red[1200 + tid*16 + j]; }
    atomicAdd(&bnS1[tid], a1);
    atomicAdd(&bnS1[80 + tid], a2);
  }
}

// -------------------------------- final BN+ReLU fused with global_add_pool
__global__ __launch_bounds__(256) void k_bnpool(const float* __restrict__ out2,
    const float* __restrict__ bnSp, const float* __restrict__ sc,
    const float* __restrict__ bb, const int* __restrict__ batch,
    float* __restrict__ pooled){
  int i = blockIdx.x*256 + threadIdx.x;
  if (i >= NN*75) return;
  int n = i / 75, f = i - n*75;
  float mu = bnSp[f] * (1.f/NN);
  float var = bnSp[80 + f] * (1.f/NN) - mu*mu;
  float v = fmaxf((out2[i] - mu) / sqrtf(var + 1e-5f) * sc[f] + bb[f], 0.f);
  atomicAdd(&pooled[batch[n]*75 + f], v);
}

__global__ __launch_bounds__(256) void k_head(const float* __restrict__ pooled,
    const float* __restrict__ W1, const float* __restrict__ b1,
    const float* __restrict__ W2, const float* __restrict__ b2,
    const float* __restrict__ W3, const float* __restrict__ b3,
    float* __restrict__ out){
  __shared__ float pl[64*75];
  __shared__ float w1[75*50];
  __shared__ float z1[64*50];
  __shared__ float w2[50*25];
  __shared__ float z2[64*25];
  __shared__ float w3[25];
  __shared__ float bb1[50], bb2[25];
  int tid = threadIdx.x;
  for (int i = tid; i < 64*75; i += 256) pl[i] = pooled[i];
  for (int i = tid; i < 75*50; i += 256) w1[i] = W1[i];
  for (int i = tid; i < 50*25; i += 256) w2[i] = W2[i];
  if (tid < 25) w3[tid] = W3[tid];
  if (tid < 50) bb1[tid] = b1[tid];
  if (tid < 25) bb2[tid] = b2[tid];
  __syncthreads();
  for (int o = tid; o < 64*50; o += 256){
    int g = o / 50, j = o - g*50;
    float acc = bb1[j];
    for (int c = 0; c < 75; ++c) acc += pl[g*75 + c] * w1[c*50 + j];
    z1[o] = fmaxf(acc, 0.f);
  }
  __syncthreads();
  for (int o = tid; o < 64*25; o += 256){
    int g = o / 25, j = o - g*25;
    float acc = bb2[j];
    for (int c = 0; c < 50; ++c) acc += z1[g*50 + c] * w2[c*25 + j];
    z2[o] = fmaxf(acc, 0.f);
  }
  __syncthreads();
  if (tid < 64){
    float acc = b3[0];
    for (int c = 0; c < 25; ++c) acc += z2[tid*25 + c] * w3[c];
    out[tid] = acc;
  }
}

// ---------------------------------------------------------------- launcher
extern "C" void kernel_launch(void* const* d_in, const int* in_sizes, int n_in,
                              void* d_out, int out_size, void* d_ws, size_t ws_size,
                              hipStream_t stream){
  const float* x     = (const float*)d_in[0];
  const int*   ei    = (const int*)  d_in[1];
  const int*   batch = (const int*)  d_in[2];
  const float* plW   = (const float*)d_in[3];
  const float* plb   = (const float*)d_in[4];
  const float* preW  = (const float*)d_in[5];
  const float* preb  = (const float*)d_in[6];
  const float* postW = (const float*)d_in[7];
  const float* postb = (const float*)d_in[8];
  const float* linW  = (const float*)d_in[9];
  const float* linb  = (const float*)d_in[10];
  const float* bns   = (const float*)d_in[11];
  const float* bnb   = (const float*)d_in[12];
  const float* W1    = (const float*)d_in[13];
  const float* b1    = (const float*)d_in[14];
  const float* W2    = (const float*)d_in[15];
  const float* b2    = (const float*)d_in[16];
  const float* W3    = (const float*)d_in[17];
  const float* b3    = (const float*)d_in[18];
  float* out = (float*)d_out;

  // workspace layout (~55 MB)
  float* h0    = (float*)d_ws;                 // 750000
  float* out2  = h0 + 750000;                  // 750000
  float* z     = out2 + 750000;                // 750000
  float* out1  = z + 750000;                   // 10000*960 = 9.6M
  float* Wcat  = out1 + (size_t)NN*ROW1;       // 4*75*1152
  float* W45   = Wcat + NL*75*WCN;             // 4*5*300*48
  float* pooled= W45 + NL*NT*300*48;           // 4800
  float* bnS   = pooled + 4800;                // 4*160
  int* cnt = (int*)(bnS + NL*160);
  int* off = cnt + NN;
  int* cur = off + NN + 1;
  int* csr = cur + NN;

  hipMemsetAsync(cnt, 0, NN*sizeof(int), stream);
  hipMemsetAsync(bnS, 0, NL*160*sizeof(float), stream);
  hipMemsetAsync(pooled, 0, 4800*sizeof(float), stream);
  k_init_h<<<(NN*NF + 255)/256, 256, 0, stream>>>(x, plW, plb, h0);
  k_count<<<(NE + 255)/256, 256, 0, stream>>>(ei, cnt);
  k_scan<<<1, 1024, 0, stream>>>(cnt, off, cur);
  k_scatter<<<(NE + 255)/256, 256, 0, stream>>>(ei, cur, csr);
  k_buildWcat<<<(NL*75*WCN + 255)/256, 256, 0, stream>>>(preW, postW, Wcat);
  k_buildW45<<<(NL*NT*300*48 + 255)/256, 256, 0, stream>>>(postW, W45);

  for (int l = 0; l < NL; ++l){
    const float* src = (l == 0) ? h0 : out2;
    const float* bnSp = bnS + (l > 0 ? (l-1)*160 : 0);
    const float* sc = bns + (l > 0 ? (l-1)*75 : 0);
    const float* bb = bnb + (l > 0 ? (l-1)*75 : 0);
    k_gemm1<<<157*9, 256, 0, stream>>>(src, Wcat, preb, bnSp, sc, bb, (l > 0),
                                       out1, z, l);
    k_aggpost<<<313*NT, 256, 0, stream>>>(out1, z, off, csr, W45, postb, l);
    k_lin<<<157, 256, 0, stream>>>(z, linW, linb, out2, bnS + l*160, l);
  }

  k_bnpool<<<(NN*NF + 255)/256, 256, 0, stream>>>(out2, bnS + 3*160,
                                                  bns + 3*75, bnb + 3*75, batch, pooled);
  k_head<<<1, 256, 0, stream>>>(pooled, W1, b1, W2, b2, W3, b3, out);
}

// Round 4
// 1030.327 us; speedup vs baseline: 1.1717x; 1.1717x over previous
//
#include <hip/hip_runtime.h>

#define NN 10000
#define NE 160000
#define NG 64
#define NT 5
#define NF 75
#define NL 4
#define LOG17 2.8332133f  /* log(17.0) */
#define ROWB 384          /* bf16 B row stride (375 used) */
#define WCN 896           /* Wcat cols: B 0..374 | base 384..758 | y0 768..842 | pad */

__device__ __forceinline__ unsigned short f2bf(float x){
  unsigned u = __float_as_uint(x);
  unsigned r = (u + 0x7FFFu + ((u >> 16) & 1u)) >> 16;
  return (unsigned short)r;
}

// ---------------------------------------------------------------- setup
__global__ __launch_bounds__(256) void k_init_h(const float* __restrict__ x,
    const float* __restrict__ W, const float* __restrict__ b, float* __restrict__ h){
  int i = blockIdx.x*256 + threadIdx.x;
  if (i >= NN*NF) return;
  int n = i / NF, f = i - n*NF;
  h[i] = x[2*n]*W[f] + x[2*n+1]*W[NF+f] + b[f];
}

__global__ __launch_bounds__(256) void k_count(const int* __restrict__ ei, int* __restrict__ cnt){
  int e = blockIdx.x*256 + threadIdx.x;
  if (e < NE) atomicAdd(&cnt[ei[NE + e]], 1);   // row 1 = dst
}

__global__ __launch_bounds__(1024) void k_scan(const int* __restrict__ cnt,
    int* __restrict__ off, int* __restrict__ cur){
  __shared__ int buf[1024];
  __shared__ int carry;
  int tid = threadIdx.x;
  if (tid == 0) carry = 0;
  __syncthreads();
  for (int base = 0; base < NN; base += 1024){
    int i = base + tid;
    int v = (i < NN) ? cnt[i] : 0;
    buf[tid] = v;
    __syncthreads();
    for (int d = 1; d < 1024; d <<= 1){
      int t = (tid >= d) ? buf[tid - d] : 0;
      __syncthreads();
      buf[tid] += t;
      __syncthreads();
    }
    int c = carry;
    if (i < NN){ int ex = c + buf[tid] - v; off[i] = ex; cur[i] = ex; }
    int tot = buf[1023];
    __syncthreads();
    if (tid == 0) carry = c + tot;
    __syncthreads();
  }
  if (tid == 0) off[NN] = NE;
}

__global__ __launch_bounds__(256) void k_scatter(const int* __restrict__ ei,
    int* __restrict__ cur, int* __restrict__ csr){
  int e = blockIdx.x*256 + threadIdx.x;
  if (e < NE){
    int d = ei[NE + e];
    int p = atomicAdd(&cur[d], 1);
    csr[p] = ei[e];   // src node
  }
}

// Wcat[l][75][896]
__global__ __launch_bounds__(256) void k_buildWcat(const float* __restrict__ preW,
    const float* __restrict__ postW, float* __restrict__ Wcat){
  int idx = blockIdx.x*256 + threadIdx.x;
  if (idx >= NL*75*WCN) return;
  int l = idx / (75*WCN);
  int rem = idx - l*75*WCN;
  int c = rem / WCN, j = rem - c*WCN;
  float v = 0.f;
  if (j < 375){
    int t = j/75, f = j - t*75;
    v = preW[(size_t)((l*NT + t)*150 + 75 + c)*75 + f];
  } else if (j >= 384 && j < 759){
    int jj = j - 384; int t = jj/75, f = jj - t*75;
    v = preW[(size_t)((l*NT + t)*150 + c)*75 + f];
  } else if (j >= 768 && j < 843){
    int jj = j - 768; int t = jj/15, f2 = jj - t*15;
    v = postW[(size_t)((l*NT + t)*975 + c)*15 + f2];
  }
  Wcat[idx] = v;
}

// W45[l][t][300][64] f32: col = 4*(f48/3) + f48%3 ; col%4==3 -> 0
__global__ __launch_bounds__(256) void k_buildW45(const float* __restrict__ postW,
    float* __restrict__ W45){
  int idx = blockIdx.x*256 + threadIdx.x;
  if (idx >= NL*NT*300*64) return;
  int l = idx / (NT*300*64);
  int rem = idx - l*NT*300*64;
  int t = rem / (300*64);
  int rem2 = rem - t*300*64;
  int c = rem2 / 64, col = rem2 - c*64;
  int g3 = col >> 2, e = col & 3;
  float v = 0.f;
  if (e < 3){
    int f48 = g3*3 + e;             // [0,48)
    int g = f48/15, f2 = f48 - g*15;
    if (g < 3)
      v = postW[(size_t)((l*NT + t)*975 + 75 + g*300 + c)*15 + f2];
  }
  W45[idx] = v;
}

// ------ GEMM1: [B(bf16) | base(+preb) | y0] = src(BN?) @ Wcat.  M=10000,K=75
__global__ __launch_bounds__(256) void k_gemm1(const float* __restrict__ src,
    const float* __restrict__ Wcat, const float* __restrict__ preb,
    const float* __restrict__ bnSp, const float* __restrict__ sc,
    const float* __restrict__ bb, int use_bn,
    unsigned short* __restrict__ out1b, float* __restrict__ baseb,
    float* __restrict__ z, int l){
  __shared__ float As[75][68];
  __shared__ float Ws[75][128];
  int tid = threadIdx.x;
  int bid = blockIdx.x;
  int nt = bid / 7, jt = bid - nt*7;
  int n0 = nt*64, j0 = jt*128;

  for (int idx = tid; idx < 64*75; idx += 256){
    int i = idx/75, c = idx - i*75;
    float v = (n0 + i < NN) ? src[(size_t)n0*75 + idx] : 0.f;
    if (use_bn){
      float mu = bnSp[c] * (1.f/NN);
      float var = bnSp[80 + c] * (1.f/NN) - mu*mu;
      v = fmaxf((v - mu) / sqrtf(var + 1e-5f) * sc[c] + bb[c], 0.f);
    }
    As[c][i] = v;
  }
  const float* wg = Wcat + (size_t)l*75*WCN;
  for (int idx = tid; idx < 75*128; idx += 256){
    int c = idx >> 7, j = idx & 127;
    Ws[c][j] = wg[(size_t)c*WCN + j0 + j];
  }
  __syncthreads();

  int jj = tid >> 4, n4 = tid & 15;
  float acc[4][8];
  #pragma unroll
  for (int i = 0; i < 4; ++i)
    #pragma unroll
    for (int j = 0; j < 8; ++j) acc[i][j] = 0.f;

  for (int c = 0; c < 75; ++c){
    float4 a = *reinterpret_cast<const float4*>(&As[c][n4*4]);
    float4 w0 = *reinterpret_cast<const float4*>(&Ws[c][jj*8]);
    float4 w1 = *reinterpret_cast<const float4*>(&Ws[c][jj*8 + 4]);
    float av[4] = {a.x, a.y, a.z, a.w};
    float wv[8] = {w0.x, w0.y, w0.z, w0.w, w1.x, w1.y, w1.z, w1.w};
    #pragma unroll
    for (int i = 0; i < 4; ++i)
      #pragma unroll
      for (int j = 0; j < 8; ++j) acc[i][j] += av[i]*wv[j];
  }

  #pragma unroll
  for (int i = 0; i < 4; ++i){
    int n = n0 + n4*4 + i;
    if (n >= NN) continue;
    #pragma unroll
    for (int j = 0; j < 8; ++j){
      int col = j0 + jj*8 + j;
      float v = acc[i][j];
      if (col < 375){
        out1b[(size_t)n*ROWB + col] = f2bf(v);
      } else if (col >= 384 && col < 759){
        baseb[(size_t)n*384 + (col - 384)] = v + preb[l*375 + (col - 384)];
      } else if (col >= 768 && col < 843){
        z[(size_t)n*75 + (col - 768)] = v;
      }
    }
  }
}

// ---- fused gather(bf16) + 5-tower post-GEMM + scalers + lin + BN-sums
// block = 16 nodes x 16 thr/node (24 feats each). 256 threads.
__global__ __launch_bounds__(256, 3) void k_aggpost(
    const unsigned short* __restrict__ out1b, const float* __restrict__ baseb,
    const float* __restrict__ z,
    const int* __restrict__ off, const int* __restrict__ csr,
    const float* __restrict__ W45, const float* __restrict__ postb,
    const float* __restrict__ linW, const float* __restrict__ linb,
    float* __restrict__ out2, float* __restrict__ bnS1, int l){
  __shared__ float As[300][20];     // also reused as red1/red2 in lin phase
  __shared__ float part[48][18];
  __shared__ float zmid[16][78];
  __shared__ float dln[16];
  int tid = threadIdx.x;
  int n0 = blockIdx.x * 16;
  int nl = tid >> 4, r = tid & 15;
  int n = n0 + nl;                  // NN % 16 == 0 -> always valid

  // ---------- gather-aggregate (bf16 rows, 24 feats/thread)
  float s[24], ss[24], mn[24], mx[24];
  #pragma unroll
  for (int j = 0; j < 24; ++j){ s[j]=0.f; ss[j]=0.f; mn[j]=3.4e38f; mx[j]=-3.4e38f; }

#define ST(v,J){ float _v=(v); s[J]+=_v; ss[J]+=_v*_v; mn[J]=fminf(mn[J],_v); mx[J]=fmaxf(mx[J],_v); }
#define PROC(X,J){ \
  ST(__uint_as_float((X).x<<16), J)   ST(__uint_as_float((X).x&0xFFFF0000u), J+1) \
  ST(__uint_as_float((X).y<<16), J+2) ST(__uint_as_float((X).y&0xFFFF0000u), J+3) \
  ST(__uint_as_float((X).z<<16), J+4) ST(__uint_as_float((X).z&0xFFFF0000u), J+5) \
  ST(__uint_as_float((X).w<<16), J+6) ST(__uint_as_float((X).w&0xFFFF0000u), J+7) }

  int e0 = off[n], e1 = off[n+1];
  int deg = e1 - e0;
  float d = (float)(deg > 0 ? deg : 1);
  {
    size_t roff = (size_t)r*24;
    int k = e0;
    for (; k + 2 <= e1; k += 2){
      const uint4* p0 = reinterpret_cast<const uint4*>(out1b + (size_t)csr[k]*ROWB + roff);
      const uint4* p1 = reinterpret_cast<const uint4*>(out1b + (size_t)csr[k+1]*ROWB + roff);
      uint4 x0 = p0[0], x1 = p0[1], x2 = p0[2];
      uint4 y0 = p1[0], y1 = p1[1], y2 = p1[2];
      PROC(x0,0) PROC(x1,8) PROC(x2,16)
      PROC(y0,0) PROC(y1,8) PROC(y2,16)
    }
    if (k < e1){
      const uint4* p0 = reinterpret_cast<const uint4*>(out1b + (size_t)csr[k]*ROWB + roff);
      uint4 x0 = p0[0], x1 = p0[1], x2 = p0[2];
      PROC(x0,0) PROC(x1,8) PROC(x2,16)
    }
  }
#undef PROC
#undef ST

  if (deg > 0){
    #pragma unroll
    for (int j = 0; j < 24; ++j){
      int f = r*24 + j;
      if (f < 375){
        float bs = baseb[(size_t)n*384 + f];
        float mb = s[j] / d;
        float var = ss[j] / d - mb*mb;
        s[j]  = bs + mb;
        ss[j] = sqrtf(fmaxf(var, 0.f) + 1e-5f);
        mn[j] = bs + mn[j];
        mx[j] = bs + mx[j];
      }
    }
  } else {
    #pragma unroll
    for (int j = 0; j < 24; ++j){ s[j]=0.f; ss[j]=sqrtf(1e-5f); mn[j]=0.f; mx[j]=0.f; }
  }
  if (r == 0) dln[nl] = d;

  // ---------- per-tower: stage As, GEMM K=300 N=48, scaler epilogue
  int gq = tid & 15, fo = tid >> 4;
  for (int t = 0; t < NT; ++t){
    #pragma unroll
    for (int j = 0; j < 24; ++j){
      int f = r*24 + j;
      int u = f - t*75;
      if (f < 375 && u >= 0 && u < 75){
        As[u][nl] = s[j]; As[75+u][nl] = mn[j];
        As[150+u][nl] = mx[j]; As[225+u][nl] = ss[j];
      }
    }
    __syncthreads();
    float a0 = 0.f, a1 = 0.f, a2 = 0.f;
    const float4* wp = reinterpret_cast<const float4*>(W45 + (size_t)((l*NT + t)*300)*64);
    #pragma unroll 4
    for (int cc = 0; cc < 300; ++cc){
      float a = As[cc][gq];
      float4 w = wp[cc*16 + fo];
      a0 += a*w.x; a1 += a*w.y; a2 += a*w.z;
    }
    part[fo*3+0][gq] = a0; part[fo*3+1][gq] = a1; part[fo*3+2][gq] = a2;
    __syncthreads();
    if (tid < 240){
      int nl2 = tid / 15, f2 = tid - nl2*15;
      int nn = n0 + nl2;
      float dd = dln[nl2];
      float logd = logf(dd + 1.f);
      float amp = logd * (1.f/LOG17), att = LOG17 / logd;
      float g0 = part[f2][nl2], g1 = part[15+f2][nl2], g2 = part[30+f2][nl2];
      zmid[nl2][t*15+f2] = z[(size_t)nn*75 + t*15+f2] + g0 + amp*g1 + att*g2
                           + postb[(l*NT+t)*15 + f2];
    }
    // no barrier: next-iter As writes touch a different region than part/zmid;
    // the next __syncthreads() (after As staging) orders everything.
  }
  __syncthreads();

  // ---------- lin: out_mid @ linW + linb, with BN partial sums
  int lnl = tid & 15, oo = tid >> 4;
  int o0 = oo*5;
  float lacc[5] = {0.f,0.f,0.f,0.f,0.f};
  const float* lw = linW + (size_t)l*5625;
  if (o0 < 75){
    for (int c = 0; c < 75; ++c){
      float a = zmid[lnl][c];
      #pragma unroll
      for (int k = 0; k < 5; ++k) lacc[k] += a * lw[c*75 + o0 + k];
    }
  }
  float* red1 = &As[0][0];
  float* red2 = red1 + 80*18;
  if (o0 < 75){
    int nn = n0 + lnl;
    #pragma unroll
    for (int k = 0; k < 5; ++k){
      float v = lacc[k] + linb[l*75 + o0 + k];
      out2[(size_t)nn*75 + o0 + k] = v;
      red1[(o0+k)*18 + lnl] = v;
      red2[(o0+k)*18 + lnl] = v*v;
    }
  }
  __syncthreads();
  if (tid < 75){
    float b1 = 0.f, b2 = 0.f;
    #pragma unroll
    for (int jj = 0; jj < 16; ++jj){ b1 += red1[tid*18+jj]; b2 += red2[tid*18+jj]; }
    atomicAdd(&bnS1[tid], b1);
    atomicAdd(&bnS1[80+tid], b2);
  }
}

// -------------------------------- final BN+ReLU fused with global_add_pool
__global__ __launch_bounds__(256) void k_bnpool(const float* __restrict__ out2,
    const float* __restrict__ bnSp, const float* __restrict__ sc,
    const float* __restrict__ bb, const int* __restrict__ batch,
    float* __restrict__ pooled){
  int i = blockIdx.x*256 + threadIdx.x;
  if (i >= NN*75) return;
  int n = i / 75, f = i - n*75;
  float mu = bnSp[f] * (1.f/NN);
  float var = bnSp[80 + f] * (1.f/NN) - mu*mu;
  float v = fmaxf((out2[i] - mu) / sqrtf(var + 1e-5f) * sc[f] + bb[f], 0.f);
  atomicAdd(&pooled[batch[n]*75 + f], v);
}

__global__ __launch_bounds__(256) void k_head(const float* __restrict__ pooled,
    const float* __restrict__ W1, const float* __restrict__ b1,
    const float* __restrict__ W2, const float* __restrict__ b2,
    const float* __restrict__ W3, const float* __restrict__ b3,
    float* __restrict__ out){
  __shared__ float pl[64*75];
  __shared__ float w1[75*50];
  __shared__ float z1[64*50];
  __shared__ float w2[50*25];
  __shared__ float z2[64*25];
  __shared__ float w3[25];
  __shared__ float bb1[50], bb2[25];
  int tid = threadIdx.x;
  for (int i = tid; i < 64*75; i += 256) pl[i] = pooled[i];
  for (int i = tid; i < 75*50; i += 256) w1[i] = W1[i];
  for (int i = tid; i < 50*25; i += 256) w2[i] = W2[i];
  if (tid < 25) w3[tid] = W3[tid];
  if (tid < 50) bb1[tid] = b1[tid];
  if (tid < 25) bb2[tid] = b2[tid];
  __syncthreads();
  for (int o = tid; o < 64*50; o += 256){
    int g = o / 50, j = o - g*50;
    float acc = bb1[j];
    for (int c = 0; c < 75; ++c) acc += pl[g*75 + c] * w1[c*50 + j];
    z1[o] = fmaxf(acc, 0.f);
  }
  __syncthreads();
  for (int o = tid; o < 64*25; o += 256){
    int g = o / 25, j = o - g*25;
    float acc = bb2[j];
    for (int c = 0; c < 50; ++c) acc += z1[g*50 + c] * w2[c*25 + j];
    z2[o] = fmaxf(acc, 0.f);
  }
  __syncthreads();
  if (tid < 64){
    float acc = b3[0];
    for (int c = 0; c < 25; ++c) acc += z2[tid*25 + c] * w3[c];
    out[tid] = acc;
  }
}

// ---------------------------------------------------------------- launcher
extern "C" void kernel_launch(void* const* d_in, const int* in_sizes, int n_in,
                              void* d_out, int out_size, void* d_ws, size_t ws_size,
                              hipStream_t stream){
  const float* x     = (const float*)d_in[0];
  const int*   ei    = (const int*)  d_in[1];
  const int*   batch = (const int*)  d_in[2];
  const float* plW   = (const float*)d_in[3];
  const float* plb   = (const float*)d_in[4];
  const float* preW  = (const float*)d_in[5];
  const float* preb  = (const float*)d_in[6];
  const float* postW = (const float*)d_in[7];
  const float* postb = (const float*)d_in[8];
  const float* linW  = (const float*)d_in[9];
  const float* linb  = (const float*)d_in[10];
  const float* bns   = (const float*)d_in[11];
  const float* bnb   = (const float*)d_in[12];
  const float* W1    = (const float*)d_in[13];
  const float* b1    = (const float*)d_in[14];
  const float* W2    = (const float*)d_in[15];
  const float* b2    = (const float*)d_in[16];
  const float* W3    = (const float*)d_in[17];
  const float* b3    = (const float*)d_in[18];
  float* out = (float*)d_out;

  // workspace layout (~32 MB)
  float* h0    = (float*)d_ws;                     // 750000
  float* out2v = h0 + 750000;                      // 750000
  float* zv    = out2v + 750000;                   // 750000
  float* baseb = zv + 750000;                      // NN*384
  float* Wcat  = baseb + (size_t)NN*384;           // 4*75*896
  float* W45   = Wcat + NL*75*WCN;                 // 4*5*300*64
  float* pooled= W45 + NL*NT*300*64;               // 4800
  float* bnS   = pooled + 4800;                    // 4*160
  unsigned short* out1b = (unsigned short*)(bnS + NL*160);  // NN*384 ushorts (16B-aligned)
  int* cnt = (int*)(out1b + (size_t)NN*ROWB);
  int* off = cnt + NN;
  int* cur = off + NN + 1;
  int* csr = cur + NN;

  hipMemsetAsync(cnt, 0, NN*sizeof(int), stream);
  hipMemsetAsync(bnS, 0, NL*160*sizeof(float), stream);
  hipMemsetAsync(pooled, 0, 4800*sizeof(float), stream);
  k_init_h<<<(NN*NF + 255)/256, 256, 0, stream>>>(x, plW, plb, h0);
  k_count<<<(NE + 255)/256, 256, 0, stream>>>(ei, cnt);
  k_scan<<<1, 1024, 0, stream>>>(cnt, off, cur);
  k_scatter<<<(NE + 255)/256, 256, 0, stream>>>(ei, cur, csr);
  k_buildWcat<<<(NL*75*WCN + 255)/256, 256, 0, stream>>>(preW, postW, Wcat);
  k_buildW45<<<(NL*NT*300*64 + 255)/256, 256, 0, stream>>>(postW, W45);

  for (int l = 0; l < NL; ++l){
    const float* src = (l == 0) ? h0 : out2v;
    const float* bnSp = bnS + (l > 0 ? (l-1)*160 : 0);
    const float* sc = bns + (l > 0 ? (l-1)*75 : 0);
    const float* bb = bnb + (l > 0 ? (l-1)*75 : 0);
    k_gemm1<<<157*7, 256, 0, stream>>>(src, Wcat, preb, bnSp, sc, bb, (l > 0),
                                       out1b, baseb, zv, l);
    k_aggpost<<<NN/16, 256, 0, stream>>>(out1b, baseb, zv, off, csr, W45, postb,
                                         linW, linb, out2v, bnS + l*160, l);
  }

  k_bnpool<<<(NN*NF + 255)/256, 256, 0, stream>>>(out2v, bnS + 3*160,
                                                  bns + 3*75, bnb + 3*75, batch, pooled);
  k_head<<<1, 256, 0, stream>>>(pooled, W1, b1, W2, b2, W3, b3, out);
}